// Round 2
// baseline (682.556 us; speedup 1.0000x reference)
//
#include <hip/hip_runtime.h>
#include <hip/hip_bf16.h>

// GAT layer: xt = x@W; alpha = segment_softmax(leakyrelu(asrc[src]+adst[dst]));
// out = relu(mean_h(segment_sum(alpha*xt[src])) + bias)
// N=50000, F_IN=116, H=8, C=32, E=800000 (+N self loops)
//
// v2: weights computed once per (edge,head) in scatter (stored CSR-ordered),
//     softmax denominator via atomics, no max-subtraction (logits bounded ~8),
//     single-pass aggregate with LDS-staged weights, parallel 3-kernel scan.

#define F_IN 116
#define HC 256     // H*C
#define NHEAD 8
#define CDIM 32

// ---------------- zero scratch (cnt, cur, lsum contiguous) ----------------
__global__ void zero_k(int* __restrict__ p, int n) {
    int i = blockIdx.x * 256 + threadIdx.x;
    if (i < n) p[i] = 0;
}

// ---------------- GEMM: xt[N,256] = x[N,116] @ W[116,256] ----------------
__global__ __launch_bounds__(256) void gemm_xt(const float* __restrict__ x,
                                               const float* __restrict__ W,
                                               float* __restrict__ xt, int N) {
    __shared__ float xs[64 * F_IN];           // 29696 B
    const int t = threadIdx.x;
    const int row0 = blockIdx.x * 64;
    const int nrows = (N - row0 < 64) ? (N - row0) : 64;
    const int tot = nrows * F_IN;
    for (int i = t; i < tot; i += 256) xs[i] = x[(size_t)row0 * F_IN + i];
    __syncthreads();

    const int w = t >> 6;
    const int lane = t & 63;
    const int r0 = w * 16;

    float acc[16][4];
#pragma unroll
    for (int r = 0; r < 16; ++r)
#pragma unroll
        for (int j = 0; j < 4; ++j) acc[r][j] = 0.f;

    for (int k4 = 0; k4 < F_IN / 4; ++k4) {
        const int k = k4 * 4;
        float w0[4], w1[4], w2[4], w3[4];
#pragma unroll
        for (int j = 0; j < 4; ++j) {
            const float* Wk = W + k * HC + lane + 64 * j;
            w0[j] = Wk[0];
            w1[j] = Wk[HC];
            w2[j] = Wk[2 * HC];
            w3[j] = Wk[3 * HC];
        }
#pragma unroll
        for (int r = 0; r < 16; ++r) {
            float4 xv = *(const float4*)&xs[(r0 + r) * F_IN + k];
#pragma unroll
            for (int j = 0; j < 4; ++j)
                acc[r][j] = fmaf(xv.x, w0[j],
                            fmaf(xv.y, w1[j],
                            fmaf(xv.z, w2[j],
                            fmaf(xv.w, w3[j], acc[r][j]))));
        }
    }

#pragma unroll
    for (int r = 0; r < 16; ++r) {
        const int row = row0 + r0 + r;
        if (row < N) {
#pragma unroll
            for (int j = 0; j < 4; ++j)
                xt[(size_t)row * HC + lane + 64 * j] = acc[r][j];
        }
    }
}

// ---------------- alphas ----------------
__global__ void alphas_k(const float* __restrict__ xt,
                         const float* __restrict__ att_s,
                         const float* __restrict__ att_d,
                         float* __restrict__ asrc, float* __restrict__ adst, int NH) {
    int idx = blockIdx.x * 256 + threadIdx.x;    // n*8 + h
    if (idx >= NH) return;
    int h = idx & 7;
    int n = idx >> 3;
    const float4* xp = (const float4*)(xt + (size_t)n * HC + h * CDIM);
    const float4* sp = (const float4*)(att_s + h * CDIM);
    const float4* dp = (const float4*)(att_d + h * CDIM);
    float a = 0.f, b = 0.f;
#pragma unroll
    for (int q = 0; q < CDIM / 4; ++q) {
        float4 v = xp[q], sv = sp[q], dv = dp[q];
        a += v.x * sv.x + v.y * sv.y + v.z * sv.z + v.w * sv.w;
        b += v.x * dv.x + v.y * dv.y + v.z * dv.z + v.w * dv.w;
    }
    asrc[idx] = a;
    adst[idx] = b;
}

// ---------------- in-degree histogram ----------------
__global__ void hist_k(const int* __restrict__ dst, int* __restrict__ cnt, int E) {
    int e = blockIdx.x * 256 + threadIdx.x;
    if (e < E) atomicAdd(&cnt[dst[e]], 1);
}

// ---------------- parallel scan: 1024 elems/block ----------------
__global__ __launch_bounds__(256) void scan1_k(const int* __restrict__ cnt,
                                               int* __restrict__ offs,
                                               int* __restrict__ bsum, int N) {
    __shared__ int ts[256];
    const int t = threadIdx.x;
    const int base = blockIdx.x * 1024 + t * 4;
    int v[4];
    int s = 0;
#pragma unroll
    for (int j = 0; j < 4; ++j) {
        v[j] = (base + j < N) ? cnt[base + j] : 0;
        s += v[j];
    }
    ts[t] = s;
    __syncthreads();
    for (int off = 1; off < 256; off <<= 1) {
        int u = (t >= off) ? ts[t - off] : 0;
        __syncthreads();
        ts[t] += u;
        __syncthreads();
    }
    int run = t ? ts[t - 1] : 0;
#pragma unroll
    for (int j = 0; j < 4; ++j) {
        if (base + j < N) offs[base + j] = run;
        run += v[j];
    }
    if (t == 255) bsum[blockIdx.x] = ts[255];
}

__global__ void scan2_k(int* __restrict__ bsum, int* __restrict__ offs, int nb, int N) {
    if (threadIdx.x == 0 && blockIdx.x == 0) {
        int run = 0;
        for (int b = 0; b < nb; ++b) {
            int v = bsum[b];
            bsum[b] = run;
            run += v;
        }
        offs[N] = run;
    }
}

__global__ void scan3_k(int* __restrict__ offs, const int* __restrict__ bsum, int N) {
    int i = blockIdx.x * 256 + threadIdx.x;
    if (i < N) offs[i] += bsum[i >> 10];
}

// ---------------- CSR scatter + per-(edge,head) weights + lsum ----------------
__global__ void scatter_k(const int* __restrict__ src, const int* __restrict__ dst,
                          const int* __restrict__ offs, int* __restrict__ cur,
                          int* __restrict__ csr, float* __restrict__ csr_w,
                          float* __restrict__ lsum,
                          const float* __restrict__ asrc, const float* __restrict__ adst,
                          int E) {
    int e = blockIdx.x * 256 + threadIdx.x;
    if (e >= E) return;
    int s = src[e];
    int d = dst[e];
    int p = offs[d] + atomicAdd(&cur[d], 1);
    csr[p] = s;
    const float4* as = (const float4*)(asrc + (size_t)s * NHEAD);
    const float4* ad = (const float4*)(adst + (size_t)d * NHEAD);
    float4 a0 = as[0], a1 = as[1];
    float4 b0 = ad[0], b1 = ad[1];
    float w[NHEAD];
    w[0] = a0.x + b0.x; w[1] = a0.y + b0.y; w[2] = a0.z + b0.z; w[3] = a0.w + b0.w;
    w[4] = a1.x + b1.x; w[5] = a1.y + b1.y; w[6] = a1.z + b1.z; w[7] = a1.w + b1.w;
    float* wp = csr_w + ((size_t)p << 3);
#pragma unroll
    for (int h = 0; h < NHEAD; ++h) {
        float z = w[h];
        z = (z > 0.f) ? z : 0.2f * z;
        float wv = __expf(z);           // no max shift: |z| <~ 8, safe in fp32
        w[h] = wv;
        atomicAdd(&lsum[d * NHEAD + h], wv);
    }
    ((float4*)wp)[0] = make_float4(w[0], w[1], w[2], w[3]);
    ((float4*)wp)[1] = make_float4(w[4], w[5], w[6], w[7]);
}

// ---------------- aggregate: one block per destination node, single pass ----------------
__global__ __launch_bounds__(256) void aggregate_k(const float* __restrict__ xt,
                                                   const float* __restrict__ asrc,
                                                   const float* __restrict__ adst,
                                                   const int* __restrict__ offs,
                                                   const int* __restrict__ csr,
                                                   const float* __restrict__ csr_w,
                                                   const float* __restrict__ lsum,
                                                   const float* __restrict__ bias,
                                                   float* __restrict__ out, int N) {
    const int n = blockIdx.x;
    const int t = threadIdx.x;
    const int h = t >> 5;
    const int beg = offs[n];
    const int d = offs[n + 1] - beg;

    // self-loop weight + softmax denominator
    float zs = asrc[n * NHEAD + h] + adst[n * NHEAD + h];
    zs = (zs > 0.f) ? zs : 0.2f * zs;
    const float wself = __expf(zs);
    const float inv = 1.f / (lsum[n * NHEAD + h] + wself + 1e-16f);

    float acc = wself * xt[(size_t)n * HC + t];

    __shared__ int sidx[32];
    __shared__ float sw[32 * NHEAD];

    for (int ch = 0; ch < d; ch += 32) {
        const int m = (d - ch < 32) ? (d - ch) : 32;
        __syncthreads();
        if (t < m) sidx[t] = csr[beg + ch + t];
        if (t < (m << 3)) sw[t] = csr_w[((size_t)(beg + ch) << 3) + t];
        __syncthreads();
        int i = 0;
        for (; i + 4 <= m; i += 4) {
            int s0 = sidx[i], s1 = sidx[i + 1], s2 = sidx[i + 2], s3 = sidx[i + 3];
            float w0 = sw[i * 8 + h], w1 = sw[(i + 1) * 8 + h];
            float w2 = sw[(i + 2) * 8 + h], w3 = sw[(i + 3) * 8 + h];
            float x0 = xt[(size_t)s0 * HC + t];
            float x1 = xt[(size_t)s1 * HC + t];
            float x2 = xt[(size_t)s2 * HC + t];
            float x3 = xt[(size_t)s3 * HC + t];
            acc = fmaf(w0, x0, acc);
            acc = fmaf(w1, x1, acc);
            acc = fmaf(w2, x2, acc);
            acc = fmaf(w3, x3, acc);
        }
        for (; i < m; ++i)
            acc = fmaf(sw[i * 8 + h], xt[(size_t)sidx[i] * HC + t], acc);
    }
    acc *= inv;

    // reduce over heads, mean + bias + relu
    __shared__ float red[256];
    __syncthreads();
    red[t] = acc;
    __syncthreads();
    if (t < CDIM) {
        float v = red[t] + red[t + 32] + red[t + 64] + red[t + 96] +
                  red[t + 128] + red[t + 160] + red[t + 192] + red[t + 224];
        v = v * (1.f / NHEAD) + bias[t];
        out[n * CDIM + t] = fmaxf(v, 0.f);
    }
}

extern "C" void kernel_launch(void* const* d_in, const int* in_sizes, int n_in,
                              void* d_out, int out_size, void* d_ws, size_t ws_size,
                              hipStream_t stream) {
    const float* x     = (const float*)d_in[0];
    const int*   ei    = (const int*)d_in[1];      // [2,E] int32: row0=src, row1=dst
    const float* W     = (const float*)d_in[2];
    const float* att_s = (const float*)d_in[3];
    const float* att_d = (const float*)d_in[4];
    const float* bias  = (const float*)d_in[5];
    float* out = (float*)d_out;

    const int N = in_sizes[0] / F_IN;    // 50000
    const int E = in_sizes[1] / 2;       // 800000

    // workspace layout (all 16B-aligned; N%4==0, E%4==0)
    float* xt    = (float*)d_ws;                        // 256N
    float* asrc  = xt + (size_t)N * HC;                 // 8N
    float* adst  = asrc + (size_t)N * NHEAD;            // 8N
    int*   offs  = (int*)(adst + (size_t)N * NHEAD);    // N+4
    int*   bsum  = offs + (N + 4);                      // 64
    int*   cnt   = bsum + 64;                           // N
    int*   cur   = cnt + N;                             // N
    float* lsum  = (float*)(cur + N);                   // 8N
    int*   csr   = (int*)(lsum + (size_t)N * NHEAD);    // E
    float* csr_w = (float*)(csr + E);                   // 8E

    const int nb = (N + 1023) / 1024;

    // zero cnt+cur+lsum (contiguous, 10N ints)
    zero_k<<<(10 * N + 255) / 256, 256, 0, stream>>>(cnt, 10 * N);
    gemm_xt<<<(N + 63) / 64, 256, 0, stream>>>(x, W, xt, N);
    alphas_k<<<(N * NHEAD + 255) / 256, 256, 0, stream>>>(xt, att_s, att_d, asrc, adst, N * NHEAD);
    hist_k<<<(E + 255) / 256, 256, 0, stream>>>(ei + E, cnt, E);
    scan1_k<<<nb, 256, 0, stream>>>(cnt, offs, bsum, N);
    scan2_k<<<1, 64, 0, stream>>>(bsum, offs, nb, N);
    scan3_k<<<(N + 255) / 256, 256, 0, stream>>>(offs, bsum, N);
    scatter_k<<<(E + 255) / 256, 256, 0, stream>>>(ei, ei + E, offs, cur, csr, csr_w, lsum,
                                                   asrc, adst, E);
    aggregate_k<<<N, 256, 0, stream>>>(xt, asrc, adst, offs, csr, csr_w, lsum, bias, out, N);
}

// Round 3
// 366.924 us; speedup vs baseline: 1.8602x; 1.8602x over previous
//
#include <hip/hip_runtime.h>
#include <hip/hip_bf16.h>

// GAT layer: xt = x@W; alpha = segment_softmax(leakyrelu(asrc[src]+adst[dst]));
// out = relu(mean_h(segment_sum(alpha*xt[src])) + bias)
// N=50000, F_IN=116, H=8, C=32, E=800000 (+N self loops)
//
// v3: scatter reverted to cheap form (csr index only — v2's random 64B
//     csr_w writes + 8 atomics/edge made it 366us latency-bound at 0.4% VALU).
//     Weights computed once per (edge,head) inside aggregate's LDS staging
//     (1 exp/thread/chunk); softmax denominator accumulated inline (no max
//     shift needed: |logit| <~ 8, exp safe in fp32, ratio unchanged).

#define F_IN 116
#define HC 256     // H*C
#define NHEAD 8
#define CDIM 32

// ---------------- zero scratch (cnt, cur contiguous) ----------------
__global__ void zero_k(int* __restrict__ p, int n) {
    int i = blockIdx.x * 256 + threadIdx.x;
    if (i < n) p[i] = 0;
}

// ---------------- GEMM: xt[N,256] = x[N,116] @ W[116,256] ----------------
__global__ __launch_bounds__(256) void gemm_xt(const float* __restrict__ x,
                                               const float* __restrict__ W,
                                               float* __restrict__ xt, int N) {
    __shared__ float xs[64 * F_IN];           // 29696 B
    const int t = threadIdx.x;
    const int row0 = blockIdx.x * 64;
    const int nrows = (N - row0 < 64) ? (N - row0) : 64;
    const int tot = nrows * F_IN;
    for (int i = t; i < tot; i += 256) xs[i] = x[(size_t)row0 * F_IN + i];
    __syncthreads();

    const int w = t >> 6;
    const int lane = t & 63;
    const int r0 = w * 16;

    float acc[16][4];
#pragma unroll
    for (int r = 0; r < 16; ++r)
#pragma unroll
        for (int j = 0; j < 4; ++j) acc[r][j] = 0.f;

    for (int k4 = 0; k4 < F_IN / 4; ++k4) {
        const int k = k4 * 4;
        float w0[4], w1[4], w2[4], w3[4];
#pragma unroll
        for (int j = 0; j < 4; ++j) {
            const float* Wk = W + k * HC + lane + 64 * j;
            w0[j] = Wk[0];
            w1[j] = Wk[HC];
            w2[j] = Wk[2 * HC];
            w3[j] = Wk[3 * HC];
        }
#pragma unroll
        for (int r = 0; r < 16; ++r) {
            float4 xv = *(const float4*)&xs[(r0 + r) * F_IN + k];
#pragma unroll
            for (int j = 0; j < 4; ++j)
                acc[r][j] = fmaf(xv.x, w0[j],
                            fmaf(xv.y, w1[j],
                            fmaf(xv.z, w2[j],
                            fmaf(xv.w, w3[j], acc[r][j]))));
        }
    }

#pragma unroll
    for (int r = 0; r < 16; ++r) {
        const int row = row0 + r0 + r;
        if (row < N) {
#pragma unroll
            for (int j = 0; j < 4; ++j)
                xt[(size_t)row * HC + lane + 64 * j] = acc[r][j];
        }
    }
}

// ---------------- alphas ----------------
__global__ void alphas_k(const float* __restrict__ xt,
                         const float* __restrict__ att_s,
                         const float* __restrict__ att_d,
                         float* __restrict__ asrc, float* __restrict__ adst, int NH) {
    int idx = blockIdx.x * 256 + threadIdx.x;    // n*8 + h
    if (idx >= NH) return;
    int h = idx & 7;
    int n = idx >> 3;
    const float4* xp = (const float4*)(xt + (size_t)n * HC + h * CDIM);
    const float4* sp = (const float4*)(att_s + h * CDIM);
    const float4* dp = (const float4*)(att_d + h * CDIM);
    float a = 0.f, b = 0.f;
#pragma unroll
    for (int q = 0; q < CDIM / 4; ++q) {
        float4 v = xp[q], sv = sp[q], dv = dp[q];
        a += v.x * sv.x + v.y * sv.y + v.z * sv.z + v.w * sv.w;
        b += v.x * dv.x + v.y * dv.y + v.z * dv.z + v.w * dv.w;
    }
    asrc[idx] = a;
    adst[idx] = b;
}

// ---------------- in-degree histogram ----------------
__global__ void hist_k(const int* __restrict__ dst, int* __restrict__ cnt, int E) {
    int e = blockIdx.x * 256 + threadIdx.x;
    if (e < E) atomicAdd(&cnt[dst[e]], 1);
}

// ---------------- parallel scan: 1024 elems/block ----------------
__global__ __launch_bounds__(256) void scan1_k(const int* __restrict__ cnt,
                                               int* __restrict__ offs,
                                               int* __restrict__ bsum, int N) {
    __shared__ int ts[256];
    const int t = threadIdx.x;
    const int base = blockIdx.x * 1024 + t * 4;
    int v[4];
    int s = 0;
#pragma unroll
    for (int j = 0; j < 4; ++j) {
        v[j] = (base + j < N) ? cnt[base + j] : 0;
        s += v[j];
    }
    ts[t] = s;
    __syncthreads();
    for (int off = 1; off < 256; off <<= 1) {
        int u = (t >= off) ? ts[t - off] : 0;
        __syncthreads();
        ts[t] += u;
        __syncthreads();
    }
    int run = t ? ts[t - 1] : 0;
#pragma unroll
    for (int j = 0; j < 4; ++j) {
        if (base + j < N) offs[base + j] = run;
        run += v[j];
    }
    if (t == 255) bsum[blockIdx.x] = ts[255];
}

__global__ void scan2_k(int* __restrict__ bsum, int* __restrict__ offs, int nb, int N) {
    if (threadIdx.x == 0 && blockIdx.x == 0) {
        int run = 0;
        for (int b = 0; b < nb; ++b) {
            int v = bsum[b];
            bsum[b] = run;
            run += v;
        }
        offs[N] = run;
    }
}

__global__ void scan3_k(int* __restrict__ offs, const int* __restrict__ bsum, int N) {
    int i = blockIdx.x * 256 + threadIdx.x;
    if (i < N) offs[i] += bsum[i >> 10];
}

// ---------------- CSR scatter (index only) ----------------
__global__ void scatter_k(const int* __restrict__ src, const int* __restrict__ dst,
                          const int* __restrict__ offs, int* __restrict__ cur,
                          int* __restrict__ csr, int E) {
    int e = blockIdx.x * 256 + threadIdx.x;
    if (e >= E) return;
    int d = dst[e];
    int p = offs[d] + atomicAdd(&cur[d], 1);
    csr[p] = src[e];
}

// ---------------- aggregate: one block per destination, single pass ----------------
// 256 threads. For the fma loop: t = h*32 + c (head h, channel c).
// For weight staging: edge j = t>>3, head hw = t&7 (1 exp per thread per chunk).
__global__ __launch_bounds__(256) void aggregate_k(const float* __restrict__ xt,
                                                   const float* __restrict__ asrc,
                                                   const float* __restrict__ adst,
                                                   const int* __restrict__ offs,
                                                   const int* __restrict__ csr,
                                                   const float* __restrict__ bias,
                                                   float* __restrict__ out, int N) {
    const int n = blockIdx.x;
    const int t = threadIdx.x;
    const int h = t >> 5;
    const int hw = t & 7;
    const int j = t >> 3;
    const int beg = offs[n];
    const int d = offs[n + 1] - beg;

    const float adst_hw = adst[n * NHEAD + hw];   // for staged weight compute

    // self-loop term
    float zs = asrc[n * NHEAD + h] + adst[n * NHEAD + h];
    zs = (zs > 0.f) ? zs : 0.2f * zs;
    const float wself = __expf(zs);
    float acc = wself * xt[(size_t)n * HC + t];
    float wsum = wself;      // denominator, accumulated redundantly per head-group

    __shared__ int sidx[32];
    __shared__ float sw[256];

    for (int ch = 0; ch < d; ch += 32) {
        const int m = (d - ch < 32) ? (d - ch) : 32;
        __syncthreads();
        if (t < m) sidx[t] = csr[beg + ch + t];
        __syncthreads();
        if (j < m) {
            float z = asrc[sidx[j] * NHEAD + hw] + adst_hw;
            z = (z > 0.f) ? z : 0.2f * z;
            sw[t] = __expf(z);                     // sw[j*8 + hw]
        }
        __syncthreads();
        int i = 0;
        for (; i + 4 <= m; i += 4) {
            int s0 = sidx[i], s1 = sidx[i + 1], s2 = sidx[i + 2], s3 = sidx[i + 3];
            float w0 = sw[i * 8 + h], w1 = sw[(i + 1) * 8 + h];
            float w2 = sw[(i + 2) * 8 + h], w3 = sw[(i + 3) * 8 + h];
            float x0 = xt[(size_t)s0 * HC + t];
            float x1 = xt[(size_t)s1 * HC + t];
            float x2 = xt[(size_t)s2 * HC + t];
            float x3 = xt[(size_t)s3 * HC + t];
            acc = fmaf(w0, x0, acc);
            acc = fmaf(w1, x1, acc);
            acc = fmaf(w2, x2, acc);
            acc = fmaf(w3, x3, acc);
            wsum += (w0 + w1) + (w2 + w3);
        }
        for (; i < m; ++i) {
            float w = sw[i * 8 + h];
            acc = fmaf(w, xt[(size_t)sidx[i] * HC + t], acc);
            wsum += w;
        }
    }
    acc /= (wsum + 1e-16f);

    // reduce over heads, mean + bias + relu
    __shared__ float red[256];
    __syncthreads();
    red[t] = acc;
    __syncthreads();
    if (t < CDIM) {
        float v = red[t] + red[t + 32] + red[t + 64] + red[t + 96] +
                  red[t + 128] + red[t + 160] + red[t + 192] + red[t + 224];
        v = v * (1.f / NHEAD) + bias[t];
        out[n * CDIM + t] = fmaxf(v, 0.f);
    }
}

extern "C" void kernel_launch(void* const* d_in, const int* in_sizes, int n_in,
                              void* d_out, int out_size, void* d_ws, size_t ws_size,
                              hipStream_t stream) {
    const float* x     = (const float*)d_in[0];
    const int*   ei    = (const int*)d_in[1];      // [2,E] int32: row0=src, row1=dst
    const float* W     = (const float*)d_in[2];
    const float* att_s = (const float*)d_in[3];
    const float* att_d = (const float*)d_in[4];
    const float* bias  = (const float*)d_in[5];
    float* out = (float*)d_out;

    const int N = in_sizes[0] / F_IN;    // 50000
    const int E = in_sizes[1] / 2;       // 800000

    // workspace layout
    float* xt   = (float*)d_ws;                        // 256N
    float* asrc = xt + (size_t)N * HC;                 // 8N
    float* adst = asrc + (size_t)N * NHEAD;            // 8N
    int*   offs = (int*)(adst + (size_t)N * NHEAD);    // N+4
    int*   bsum = offs + (N + 4);                      // 64
    int*   cnt  = bsum + 64;                           // N
    int*   cur  = cnt + N;                             // N
    int*   csr  = cur + N;                             // E

    const int nb = (N + 1023) / 1024;

    zero_k<<<(2 * N + 255) / 256, 256, 0, stream>>>(cnt, 2 * N);   // cnt + cur
    gemm_xt<<<(N + 63) / 64, 256, 0, stream>>>(x, W, xt, N);
    alphas_k<<<(N * NHEAD + 255) / 256, 256, 0, stream>>>(xt, att_s, att_d, asrc, adst, N * NHEAD);
    hist_k<<<(E + 255) / 256, 256, 0, stream>>>(ei + E, cnt, E);
    scan1_k<<<nb, 256, 0, stream>>>(cnt, offs, bsum, N);
    scan2_k<<<1, 64, 0, stream>>>(bsum, offs, nb, N);
    scan3_k<<<(N + 255) / 256, 256, 0, stream>>>(offs, bsum, N);
    scatter_k<<<(E + 255) / 256, 256, 0, stream>>>(ei, ei + E, offs, cur, csr, E);
    aggregate_k<<<N, 256, 0, stream>>>(xt, asrc, adst, offs, csr, bias, out, N);
}